// Round 2
// baseline (265.342 us; speedup 1.0000x reference)
//
#include <hip/hip_runtime.h>
#include <hip/hip_fp16.h>

#define N 512
#define NF 257        // n_freq = N/2 + 1
#define NB 128        // batch
#define PI_F 3.14159265358979323846f
#define C_SQ2 0.70710678118654752440f

__device__ __forceinline__ float2 cmul(float2 a, float2 b) {
    return make_float2(a.x * b.x - a.y * b.y, a.x * b.y + a.y * b.x);
}
__device__ __forceinline__ void bf(float2& a, float2& b) {
    float2 t = b;
    b = make_float2(a.x - t.x, a.y - t.y);
    a = make_float2(a.x + t.x, a.y + t.y);
}
__device__ __forceinline__ void bf_tw(float2& a, float2& b, float2 w) {
    float2 t = cmul(b, w);
    b = make_float2(a.x - t.x, a.y - t.y);
    a = make_float2(a.x + t.x, a.y + t.y);
}
__device__ __forceinline__ void bf_ni(float2& a, float2& b) {   // tw = -i
    float2 t = make_float2(b.y, -b.x);
    b = make_float2(a.x - t.x, a.y - t.y);
    a = make_float2(a.x + t.x, a.y + t.y);
}
// Compiler-only ordering fence (zero instructions). HW guarantee: DS ops of a
// wave execute in issue order, so a ds_read issued after a ds_write sees the
// data; lgkmcnt is only needed for register availability, which the compiler
// tracks with counted waits. This fence just stops compiler reordering.
__device__ __forceinline__ void lds_order() {
    asm volatile("" ::: "memory");
}

// 512-pt FFT per wave, float2 AoS LDS scratch (576 float2 per wave, pad p=q+(q>>3)).
// Input contract: v[e] = x[brev9(8*l + e)] = x[64*brev3(e) + brev6(l)].
// Output: lane l holds X[64*t + l] in v[t].
__device__ __forceinline__ void fft512_core(float2 v[8], float2* st, int l) {
    const float2 w64  = make_float2(C_SQ2, -C_SQ2);    // e^{-i pi/4}
    const float2 w192 = make_float2(-C_SQ2, -C_SQ2);   // e^{-3i pi/4}
    lds_order();   // don't let this call's LDS writes hoist above a prior call's reads
    // ---- phase A: stages 1-3 in registers ----
    bf(v[0], v[1]); bf(v[2], v[3]); bf(v[4], v[5]); bf(v[6], v[7]);
    bf(v[0], v[2]); bf_ni(v[1], v[3]); bf(v[4], v[6]); bf_ni(v[5], v[7]);
    bf(v[0], v[4]); bf_tw(v[1], v[5], w64); bf_ni(v[2], v[6]); bf_tw(v[3], v[7], w192);
    // ---- transpose A->B (no hard drain; DS pipe is in-order per wave) ----
#pragma unroll
    for (int e = 0; e < 8; e++) st[9 * l + e] = v[e];
    lds_order();
    int g = l >> 3, r = l & 7;
#pragma unroll
    for (int t = 0; t < 8; t++) v[t] = st[72 * g + 9 * t + r];
    // ---- phase B: stages 4-6 ----
    float sn, cs;
    __sincosf(-(PI_F / 32.0f) * (float)r, &sn, &cs);
    float2 W1 = make_float2(cs, sn);        // w^(8r)
    float2 W2 = cmul(W1, W1);
    float2 W3 = cmul(W2, W2);
    float2 W2n = make_float2(W2.y, -W2.x);
    bf_tw(v[0], v[1], W3); bf_tw(v[2], v[3], W3); bf_tw(v[4], v[5], W3); bf_tw(v[6], v[7], W3);
    bf_tw(v[0], v[2], W2); bf_tw(v[1], v[3], W2n); bf_tw(v[4], v[6], W2); bf_tw(v[5], v[7], W2n);
    {
        float2 W1a = cmul(W1, w64);
        float2 W1n = make_float2(W1.y, -W1.x);
        float2 W1c = cmul(W1, w192);
        bf_tw(v[0], v[4], W1); bf_tw(v[1], v[5], W1a); bf_tw(v[2], v[6], W1n); bf_tw(v[3], v[7], W1c);
    }
    // ---- transpose B->C ----
    lds_order();
#pragma unroll
    for (int t = 0; t < 8; t++) st[72 * g + 9 * t + r] = v[t];
    lds_order();
#pragma unroll
    for (int t = 0; t < 8; t++) v[t] = st[72 * t + l + (l >> 3)];
    // ---- phase C: stages 7-9 ----
    __sincosf(-(PI_F / 256.0f) * (float)l, &sn, &cs);
    float2 Wc = make_float2(cs, sn);
    float2 w2 = cmul(Wc, Wc);
    float2 w4 = cmul(w2, w2);
    float2 w2n = make_float2(w2.y, -w2.x);
    bf_tw(v[0], v[1], w4); bf_tw(v[2], v[3], w4); bf_tw(v[4], v[5], w4); bf_tw(v[6], v[7], w4);
    bf_tw(v[0], v[2], w2); bf_tw(v[1], v[3], w2n); bf_tw(v[4], v[6], w2); bf_tw(v[5], v[7], w2n);
    {
        float2 Wca = cmul(Wc, w64);
        float2 Wcn = make_float2(Wc.y, -Wc.x);
        float2 Wcc = cmul(Wc, w192);
        bf_tw(v[0], v[4], Wc); bf_tw(v[1], v[5], Wca); bf_tw(v[2], v[6], Wcn); bf_tw(v[3], v[7], Wcc);
    }
}

// ---------------- zero accumulators ----------------
__global__ void zero_kernel(float* __restrict__ accH, float* __restrict__ bins,
                            float* __restrict__ meanacc) {
    int i = blockIdx.x * blockDim.x + threadIdx.x;
    if (i < NF * N) accH[i] = 0.0f;
    if (i < 2 * (NF + 1)) bins[i] = 0.0f;
    if (i < NB) meanacc[i] = 0.0f;
}

// ---------------- Hann window table (1 MB, L2-resident afterwards) ----------
__global__ __launch_bounds__(256) void hanntab_kernel(float* __restrict__ htab) {
    int i = blockIdx.x * 256 + threadIdx.x;
    int r = i >> 9, c = i & (N - 1);
    const float step = (float)N / (float)(N - 1);
    float a = -0.5f * (float)N + (float)r * step;
    float b = -0.5f * (float)N + (float)c * step;
    float rr = sqrtf(a * a + b * b);
    float h = (rr > 256.0f) ? 0.0f : 0.5f * (1.0f + cosf(rr * (PI_F / 256.0f)));
    htab[i] = h;
}

// ---------------- rowFFT of the Hann window itself (once per launch) ----------
// Hrow layout: [col 0..256][row 0..511] float2 (fp32).
__global__ __launch_bounds__(512) void hannfft_kernel(const float* __restrict__ htab,
                                                      float2* __restrict__ Hrow) {
    __shared__ float sm[9216];
    int tid = threadIdx.x;
    int w = tid >> 6, l = tid & 63;
    int rowbase = blockIdx.x << 4;
    int r1 = rowbase + 2 * w;
    int rl = __brev((unsigned)l) >> 26;                 // brev6(l)
    const int bre[8] = {0, 4, 2, 6, 1, 5, 3, 7};        // brev3(e)
    const float* h1 = htab + (size_t)r1 * N + rl;
    const float* h2 = h1 + N;                           // row r1+1

    float2 v[8];
#pragma unroll
    for (int e = 0; e < 8; e++) {
        int o = bre[e] << 6;
        v[e] = make_float2(h1[o], h2[o]);               // direct bit-reversed load
    }

    float2* st = (float2*)sm + w * 576;
    fft512_core(v, st, l);
    __syncthreads();

    float* tre = sm;            // [16][265]
    float* tim = sm + 4240;
    int lr0 = 2 * w, lr1 = lr0 + 1;
    int sl = (64 - l) & 63;
#pragma unroll
    for (int t = 0; t <= 4; t++) {
        float2 a = v[7 - t];
        float zfx = __shfl(a.x, sl);
        float zfy = __shfl(a.y, sl);
        if (l == 0) { float2 o = v[(8 - t) & 7]; zfx = o.x; zfy = o.y; }
        float2 z = v[t];
        int col = 64 * t + l;
        if (col < NF) {
            tre[lr0 * 265 + col] = 0.5f * (z.x + zfx);
            tim[lr0 * 265 + col] = 0.5f * (z.y - zfy);
            tre[lr1 * 265 + col] = 0.5f * (z.y + zfy);
            tim[lr1 * 265 + col] = 0.5f * (zfx - z.x);
        }
    }
    __syncthreads();

    int c0 = tid >> 4, rr = tid & 15;
#pragma unroll
    for (int it = 0; it < 9; it++) {
        int c = it * 32 + c0;
        if (c < NF) {
            float2 val = make_float2(tre[rr * 265 + c], tim[rr * 265 + c]);
            Hrow[(size_t)c * N + rowbase + rr] = val;
        }
    }
}

// ---------------- row FFT: 2 real rows packed per wave, Hermitian half stored ----
// Direct bit-reversed global loads (no LDS pre-permute). inter is fp16.
__global__ __launch_bounds__(512, 4) void rowfft_kernel(const float* __restrict__ x,
                                                        const float* __restrict__ htab,
                                                        float* __restrict__ meanacc,
                                                        __half2* __restrict__ inter) {
    __shared__ float sm[9216];
    __shared__ float redsum[8];
    int tid = threadIdx.x;
    int w = tid >> 6, l = tid & 63;
    int img = blockIdx.x >> 5;
    int rowbase = (blockIdx.x & 31) << 4;
    int r1 = rowbase + 2 * w;
    int rl = __brev((unsigned)l) >> 26;                 // brev6(l)
    const int bre[8] = {0, 4, 2, 6, 1, 5, 3, 7};        // brev3(e)
    const float* xr1 = x + ((size_t)img * N + r1) * N + rl;
    const float* xr2 = xr1 + N;                         // row r1+1
    const float* hr1 = htab + (size_t)r1 * N + rl;
    const float* hr2 = hr1 + N;

    float a1[8], a2[8], b1[8], b2[8];
#pragma unroll
    for (int e = 0; e < 8; e++) {
        int o = bre[e] << 6;                            // const offsets -> imm folds
        a1[e] = xr1[o]; a2[e] = xr2[o];
        b1[e] = hr1[o]; b2[e] = hr2[o];
    }

    float rsum = 0.0f;
#pragma unroll
    for (int e = 0; e < 8; e++) rsum += a1[e] + a2[e];

    float2 v[8];
#pragma unroll
    for (int e = 0; e < 8; e++) v[e] = make_float2(a1[e] * b1[e], a2[e] * b2[e]);

#pragma unroll
    for (int off = 32; off > 0; off >>= 1) rsum += __shfl_down(rsum, off);
    if (l == 0) redsum[w] = rsum;

    float2* st = (float2*)sm + w * 576;
    fft512_core(v, st, l);
    __syncthreads();   // all waves done with FFT scratch before tile reuse
    if (tid == 0) {
        float s = 0.0f;
#pragma unroll
        for (int i = 0; i < 8; i++) s += redsum[i];
        atomicAdd(meanacc + img, s);
    }

    // unpack packed rows: R1 = (Z + conj(Zflip))/2, R2 = -i(Z - conj(Zflip))/2
    __half2* tile = (__half2*)sm;    // [16][265]
    int lr0 = 2 * w, lr1 = lr0 + 1;
    int sl = (64 - l) & 63;
#pragma unroll
    for (int t = 0; t <= 4; t++) {
        float2 a = v[7 - t];
        float zfx = __shfl(a.x, sl);
        float zfy = __shfl(a.y, sl);
        if (l == 0) { float2 o = v[(8 - t) & 7]; zfx = o.x; zfy = o.y; }
        float2 z = v[t];
        int col = 64 * t + l;
        if (col < NF) {
            tile[lr0 * 265 + col] = __floats2half2_rn(0.5f * (z.x + zfx), 0.5f * (z.y - zfy));
            tile[lr1 * 265 + col] = __floats2half2_rn(0.5f * (z.y + zfy), 0.5f * (zfx - z.x));
        }
    }
    __syncthreads();

    // coalesced transposed write: 16 consecutive rows per column
    int c0 = tid >> 4, rr = tid & 15;
#pragma unroll
    for (int it = 0; it < 9; it++) {
        int c = it * 32 + c0;
        if (c < NF) {
            inter[((size_t)img * NF + c) * N + rowbase + rr] = tile[rr * 265 + c];
        }
    }
}

// ---------------- column FFT + |F|^2 half-plane accumulate ----------------
// block = 256 threads = 4 waves = 4 columns; 8 images per group with prefetch;
// direct bit-reversed loads; accH[col][k] (no shift/mirror here).
__global__ __launch_bounds__(256, 4) void colfft_kernel(const __half2* __restrict__ inter,
                                                        const float2* __restrict__ Hrow,
                                                        const float* __restrict__ meanacc,
                                                        float* __restrict__ accH) {
    __shared__ float sm[4608];
    int tid = threadIdx.x;
    int w = tid >> 6, l = tid & 63;
    int col = blockIdx.x * 4 + w;
    int colc = col < NF ? col : NF - 1;
    int b0 = blockIdx.y * 8;
    float2* st = (float2*)sm + w * 576;
    int rl = __brev((unsigned)l) >> 26;                 // brev6(l)
    const int bre[8] = {0, 4, 2, 6, 1, 5, 3, 7};        // brev3(e)

    float2 hc[8];
    const float2* hp = Hrow + (size_t)colc * N + rl;
#pragma unroll
    for (int e = 0; e < 8; e++) hc[e] = hp[bre[e] << 6];

    float mn8[8];
#pragma unroll
    for (int bi = 0; bi < 8; bi++)
        mn8[bi] = meanacc[b0 + bi] * (1.0f / ((float)N * (float)N));

    float pw[8];
#pragma unroll
    for (int t = 0; t < 8; t++) pw[t] = 0.0f;

    __half2 cur[8], nxt[8];
    const __half2* ip0 = inter + ((size_t)b0 * NF + colc) * N + rl;
#pragma unroll
    for (int e = 0; e < 8; e++) cur[e] = ip0[bre[e] << 6];

    for (int bi = 0; bi < 8; bi++) {
        if (bi < 7) {
            const __half2* np = inter + ((size_t)(b0 + bi + 1) * NF + colc) * N + rl;
#pragma unroll
            for (int e = 0; e < 8; e++) nxt[e] = np[bre[e] << 6];
        }
        float mn = mn8[bi];
        float2 v[8];
#pragma unroll
        for (int e = 0; e < 8; e++) {
            float2 z = __half22float2(cur[e]);
            v[e] = make_float2(z.x - mn * hc[e].x, z.y - mn * hc[e].y);
        }
        fft512_core(v, st, l);
#pragma unroll
        for (int t = 0; t < 8; t++)
            pw[t] += v[t].x * v[t].x + v[t].y * v[t].y;
#pragma unroll
        for (int e = 0; e < 8; e++) cur[e] = nxt[e];
    }

    if (col < NF) {
#pragma unroll
        for (int t = 0; t < 8; t++)
            atomicAdd(&accH[(size_t)col * N + 64 * t + l], pw[t]);
    }
}

// ---------------- finalize: nps2D (with Hermitian mirror) + radial bins ------
// Output-major iteration: coalesced out2d stores; scattered accH reads stay in L2.
__global__ __launch_bounds__(256) void finalize2d_kernel(const float* __restrict__ accH,
                                                         float* __restrict__ out2d,
                                                         float* __restrict__ bins) {
    __shared__ float lsum[NF];
    __shared__ float lcnt[NF];
    int t = threadIdx.x;
    for (int i = t; i < NF; i += 256) { lsum[i] = 0.0f; lcnt[i] = 0.0f; }
    __syncthreads();
    const float scale = (0.1f * 0.1f) / ((float)N * (float)N) / (float)NB;
    int idx = blockIdx.x * 256 + t;
    int stride = gridDim.x * 256;
    for (int p = idx; p < N * N; p += stride) {
        int i = p >> 9, j = p & (N - 1);
        int jm = (j + 256) & 511;
        int col, k;
        if (jm < NF) { col = jm; k = (i + 256) & 511; }        // direct half-plane
        else         { col = 256 - j; k = (256 - i) & 511; }   // Hermitian mirror
        float v = accH[((size_t)col << 9) + k] * scale;
        out2d[p] = v;                                           // coalesced store
        float xi = (float)(i - 256), yj = (float)(j - 256);
        int rad = (int)rintf(sqrtf(xi * xi + yj * yj));
        if (rad < NF) { atomicAdd(&lsum[rad], v); atomicAdd(&lcnt[rad], 1.0f); }
    }
    __syncthreads();
    for (int i = t; i < NF; i += 256) {
        if (lsum[i] != 0.0f || lcnt[i] != 0.0f) {
            atomicAdd(&bins[i], lsum[i]);
            atomicAdd(&bins[NF + 1 + i], lcnt[i]);
        }
    }
}

// ---------------- finalize: nps1D + f1D ----------------
__global__ void finalize1d_kernel(const float* __restrict__ bins, float* __restrict__ out) {
    int t = blockIdx.x * blockDim.x + threadIdx.x;
    if (t < NF) {
        out[t] = bins[t] / bins[NF + 1 + t];                 // nps1D
        out[NF + N * N + t] = (float)t * (5.0f / 256.0f);    // f1D (nyquist = 5)
    }
}

extern "C" void kernel_launch(void* const* d_in, const int* in_sizes, int n_in,
                              void* d_out, int out_size, void* d_ws, size_t ws_size,
                              hipStream_t stream) {
    const float* x = (const float*)d_in[0];
    float* out = (float*)d_out;
    char* ws = (char*)d_ws;

    float* accH    = (float*)ws;                                     // NF*N floats
    float* meanacc = (float*)(ws + (size_t)NF * N * sizeof(float));  // NB floats
    float* bins    = meanacc + NB;                                   // 2*(NF+1) floats
    size_t off_h = (size_t)NF * N * sizeof(float) + NB * sizeof(float)
                   + 2 * (NF + 1) * sizeof(float);
    off_h = (off_h + 255) & ~(size_t)255;
    float2* Hrow = (float2*)(ws + off_h);                            // [NF][N] float2 ~ 1.05 MB
    size_t off_t = off_h + (size_t)NF * N * sizeof(float2);
    off_t = (off_t + 255) & ~(size_t)255;
    float* htab = (float*)(ws + off_t);                              // [N][N] float = 1 MB
    size_t off_inter = off_t + (size_t)N * N * sizeof(float);
    off_inter = (off_inter + 255) & ~(size_t)255;
    __half2* inter = (__half2*)(ws + off_inter);   // [NB][NF][N] half2 = 67.4 MB

    zero_kernel<<<dim3((NF * N + 255) / 256), dim3(256), 0, stream>>>(accH, bins, meanacc);
    hanntab_kernel<<<dim3(N * N / 256), dim3(256), 0, stream>>>(htab);
    hannfft_kernel<<<dim3(32), dim3(512), 0, stream>>>(htab, Hrow);
    rowfft_kernel<<<dim3(NB * 32), dim3(512), 0, stream>>>(x, htab, meanacc, inter);
    colfft_kernel<<<dim3(65, 16), dim3(256), 0, stream>>>(inter, Hrow, meanacc, accH);
    finalize2d_kernel<<<dim3(256), dim3(256), 0, stream>>>(accH, out + NF, bins);
    finalize1d_kernel<<<dim3(2), dim3(256), 0, stream>>>(bins, out);
}

// Round 3
// 256.087 us; speedup vs baseline: 1.0361x; 1.0361x over previous
//
#include <hip/hip_runtime.h>
#include <hip/hip_fp16.h>

#define N 512
#define NF 257        // n_freq = N/2 + 1
#define NB 128        // batch
#define PI_F 3.14159265358979323846f
#define C_SQ2 0.70710678118654752440f

__device__ __forceinline__ float2 cmul(float2 a, float2 b) {
    return make_float2(a.x * b.x - a.y * b.y, a.x * b.y + a.y * b.x);
}
__device__ __forceinline__ void bf(float2& a, float2& b) {
    float2 t = b;
    b = make_float2(a.x - t.x, a.y - t.y);
    a = make_float2(a.x + t.x, a.y + t.y);
}
__device__ __forceinline__ void bf_tw(float2& a, float2& b, float2 w) {
    float2 t = cmul(b, w);
    b = make_float2(a.x - t.x, a.y - t.y);
    a = make_float2(a.x + t.x, a.y + t.y);
}
__device__ __forceinline__ void bf_ni(float2& a, float2& b) {   // tw = -i
    float2 t = make_float2(b.y, -b.x);
    b = make_float2(a.x - t.x, a.y - t.y);
    a = make_float2(a.x + t.x, a.y + t.y);
}
// Compiler-only ordering fence (zero instructions). HW: a wave's DS ops execute
// in issue order, so ds_read-after-ds_write through LDS is safe with only
// counted register waits (validated R1/R2: correctness held with no hard drain).
__device__ __forceinline__ void lds_order() {
    asm volatile("" ::: "memory");
}

__device__ __forceinline__ void fft_phaseA(float2 v[8]) {
    const float2 w64  = make_float2(C_SQ2, -C_SQ2);    // e^{-i pi/4}
    const float2 w192 = make_float2(-C_SQ2, -C_SQ2);   // e^{-3i pi/4}
    bf(v[0], v[1]); bf(v[2], v[3]); bf(v[4], v[5]); bf(v[6], v[7]);
    bf(v[0], v[2]); bf_ni(v[1], v[3]); bf(v[4], v[6]); bf_ni(v[5], v[7]);
    bf(v[0], v[4]); bf_tw(v[1], v[5], w64); bf_ni(v[2], v[6]); bf_tw(v[3], v[7], w192);
}
// one radix-2^3 group of stages with precomputed twiddles (used for B and C)
__device__ __forceinline__ void fft_phaseBC(float2 v[8], float2 W1, float2 W1a,
                                            float2 W1n, float2 W1c, float2 W2,
                                            float2 W2n, float2 W3) {
    bf_tw(v[0], v[1], W3); bf_tw(v[2], v[3], W3); bf_tw(v[4], v[5], W3); bf_tw(v[6], v[7], W3);
    bf_tw(v[0], v[2], W2); bf_tw(v[1], v[3], W2n); bf_tw(v[4], v[6], W2); bf_tw(v[5], v[7], W2n);
    bf_tw(v[0], v[4], W1); bf_tw(v[1], v[5], W1a); bf_tw(v[2], v[6], W1n); bf_tw(v[3], v[7], W1c);
}

// 512-pt FFT per wave (single stream), scratch = 576 float2 per wave.
// Input: v[e] = x[brev9(8l+e)] = x[64*brev3(e)+brev6(l)]; out: lane l holds X[64t+l] in v[t].
__device__ __forceinline__ void fft512_core(float2 v[8], float2* st, int l) {
    const float2 w64  = make_float2(C_SQ2, -C_SQ2);
    const float2 w192 = make_float2(-C_SQ2, -C_SQ2);
    int g = l >> 3, r = l & 7;
    lds_order();
    fft_phaseA(v);
#pragma unroll
    for (int e = 0; e < 8; e++) st[9 * l + e] = v[e];
    lds_order();
#pragma unroll
    for (int t = 0; t < 8; t++) v[t] = st[72 * g + 9 * t + r];
    float sn, cs;
    __sincosf(-(PI_F / 32.0f) * (float)r, &sn, &cs);
    float2 W1 = make_float2(cs, sn);
    float2 W2 = cmul(W1, W1);
    float2 W3 = cmul(W2, W2);
    float2 W2n = make_float2(W2.y, -W2.x);
    float2 W1a = cmul(W1, w64);
    float2 W1n = make_float2(W1.y, -W1.x);
    float2 W1c = cmul(W1, w192);
    fft_phaseBC(v, W1, W1a, W1n, W1c, W2, W2n, W3);
    lds_order();
#pragma unroll
    for (int t = 0; t < 8; t++) st[72 * g + 9 * t + r] = v[t];
    lds_order();
#pragma unroll
    for (int t = 0; t < 8; t++) v[t] = st[72 * t + l + (l >> 3)];
    __sincosf(-(PI_F / 256.0f) * (float)l, &sn, &cs);
    float2 Wc = make_float2(cs, sn);
    float2 w2 = cmul(Wc, Wc);
    float2 w4 = cmul(w2, w2);
    float2 w2n = make_float2(w2.y, -w2.x);
    float2 Wca = cmul(Wc, w64);
    float2 Wcn = make_float2(Wc.y, -Wc.x);
    float2 Wcc = cmul(Wc, w192);
    fft_phaseBC(v, Wc, Wca, Wcn, Wcc, w2, w2n, w4);
}

// Two independent 512-pt FFTs per wave, interleaved through ONE shared scratch.
// DS in-order per wave guarantees W_a < R_a < W_b < R_b memory order; while
// FFT-a waits its transpose reads, FFT-b's DS ops queue; butterflies overlap.
__device__ __forceinline__ void fft512_x2(float2 va[8], float2 vb[8], float2* st, int l) {
    const float2 w64  = make_float2(C_SQ2, -C_SQ2);
    const float2 w192 = make_float2(-C_SQ2, -C_SQ2);
    int g = l >> 3, r = l & 7;
    fft_phaseA(va); fft_phaseA(vb);
    // ---- transpose 1, interleaved ----
    lds_order();
#pragma unroll
    for (int e = 0; e < 8; e++) st[9 * l + e] = va[e];
    lds_order();
#pragma unroll
    for (int t = 0; t < 8; t++) va[t] = st[72 * g + 9 * t + r];
    lds_order();
#pragma unroll
    for (int e = 0; e < 8; e++) st[9 * l + e] = vb[e];
    lds_order();
#pragma unroll
    for (int t = 0; t < 8; t++) vb[t] = st[72 * g + 9 * t + r];
    // twiddles shared by both streams; VALU runs in DS-latency shadow
    float sn, cs;
    __sincosf(-(PI_F / 32.0f) * (float)r, &sn, &cs);
    float2 W1 = make_float2(cs, sn);
    float2 W2 = cmul(W1, W1);
    float2 W3 = cmul(W2, W2);
    float2 W2n = make_float2(W2.y, -W2.x);
    float2 W1a = cmul(W1, w64);
    float2 W1n = make_float2(W1.y, -W1.x);
    float2 W1c = cmul(W1, w192);
    fft_phaseBC(va, W1, W1a, W1n, W1c, W2, W2n, W3);
    fft_phaseBC(vb, W1, W1a, W1n, W1c, W2, W2n, W3);
    // ---- transpose 2, interleaved ----
    lds_order();
#pragma unroll
    for (int t = 0; t < 8; t++) st[72 * g + 9 * t + r] = va[t];
    lds_order();
#pragma unroll
    for (int t = 0; t < 8; t++) va[t] = st[72 * t + l + (l >> 3)];
    lds_order();
#pragma unroll
    for (int t = 0; t < 8; t++) st[72 * g + 9 * t + r] = vb[t];
    lds_order();
#pragma unroll
    for (int t = 0; t < 8; t++) vb[t] = st[72 * t + l + (l >> 3)];
    __sincosf(-(PI_F / 256.0f) * (float)l, &sn, &cs);
    float2 Wc = make_float2(cs, sn);
    float2 w2 = cmul(Wc, Wc);
    float2 w4 = cmul(w2, w2);
    float2 w2n = make_float2(w2.y, -w2.x);
    float2 Wca = cmul(Wc, w64);
    float2 Wcn = make_float2(Wc.y, -Wc.x);
    float2 Wcc = cmul(Wc, w192);
    fft_phaseBC(va, Wc, Wca, Wcn, Wcc, w2, w2n, w4);
    fft_phaseBC(vb, Wc, Wca, Wcn, Wcc, w2, w2n, w4);
}

// Hermitian unpack of one packed-pair FFT into the half2 tile.
__device__ __forceinline__ void unpack_rows(const float2 v[8], __half2* tile,
                                            int lr0, int lr1, int l, int sl) {
#pragma unroll
    for (int t = 0; t <= 4; t++) {
        float2 a = v[7 - t];
        float zfx = __shfl(a.x, sl);
        float zfy = __shfl(a.y, sl);
        if (l == 0) { float2 o = v[(8 - t) & 7]; zfx = o.x; zfy = o.y; }
        float2 z = v[t];
        int col = 64 * t + l;
        if (col < NF) {
            tile[lr0 * 265 + col] = __floats2half2_rn(0.5f * (z.x + zfx), 0.5f * (z.y - zfy));
            tile[lr1 * 265 + col] = __floats2half2_rn(0.5f * (z.y + zfy), 0.5f * (zfx - z.x));
        }
    }
}

// ---------------- zero accumulators ----------------
__global__ void zero_kernel(float* __restrict__ accH, float* __restrict__ bins,
                            float* __restrict__ meanacc) {
    int i = blockIdx.x * blockDim.x + threadIdx.x;
    if (i < NF * N) accH[i] = 0.0f;
    if (i < 2 * (NF + 1)) bins[i] = 0.0f;
    if (i < NB) meanacc[i] = 0.0f;
}

// ---------------- Hann window table (1 MB, L2-resident afterwards) ----------
__global__ __launch_bounds__(256) void hanntab_kernel(float* __restrict__ htab) {
    int i = blockIdx.x * 256 + threadIdx.x;
    int r = i >> 9, c = i & (N - 1);
    const float step = (float)N / (float)(N - 1);
    float a = -0.5f * (float)N + (float)r * step;
    float b = -0.5f * (float)N + (float)c * step;
    float rr = sqrtf(a * a + b * b);
    float h = (rr > 256.0f) ? 0.0f : 0.5f * (1.0f + cosf(rr * (PI_F / 256.0f)));
    htab[i] = h;
}

// ---------------- rowFFT of the Hann window itself (once per launch) ----------
__global__ __launch_bounds__(512) void hannfft_kernel(const float* __restrict__ htab,
                                                      float2* __restrict__ Hrow) {
    __shared__ float sm[9216];
    int tid = threadIdx.x;
    int w = tid >> 6, l = tid & 63;
    int rowbase = blockIdx.x << 4;
    int r1 = rowbase + 2 * w;
    int rl = __brev((unsigned)l) >> 26;                 // brev6(l)
    const int bre[8] = {0, 4, 2, 6, 1, 5, 3, 7};        // brev3(e)
    const float* h1 = htab + (size_t)r1 * N + rl;
    const float* h2 = h1 + N;

    float2 v[8];
#pragma unroll
    for (int e = 0; e < 8; e++) {
        int o = bre[e] << 6;
        v[e] = make_float2(h1[o], h2[o]);
    }

    float2* st = (float2*)sm + w * 576;
    fft512_core(v, st, l);
    __syncthreads();

    float* tre = sm;            // [16][265]
    float* tim = sm + 4240;
    int lr0 = 2 * w, lr1 = lr0 + 1;
    int sl = (64 - l) & 63;
#pragma unroll
    for (int t = 0; t <= 4; t++) {
        float2 a = v[7 - t];
        float zfx = __shfl(a.x, sl);
        float zfy = __shfl(a.y, sl);
        if (l == 0) { float2 o = v[(8 - t) & 7]; zfx = o.x; zfy = o.y; }
        float2 z = v[t];
        int col = 64 * t + l;
        if (col < NF) {
            tre[lr0 * 265 + col] = 0.5f * (z.x + zfx);
            tim[lr0 * 265 + col] = 0.5f * (z.y - zfy);
            tre[lr1 * 265 + col] = 0.5f * (z.y + zfy);
            tim[lr1 * 265 + col] = 0.5f * (zfx - z.x);
        }
    }
    __syncthreads();

    int c0 = tid >> 4, rr = tid & 15;
#pragma unroll
    for (int it = 0; it < 9; it++) {
        int c = it * 32 + c0;
        if (c < NF) {
            float2 val = make_float2(tre[rr * 265 + c], tim[rr * 265 + c]);
            Hrow[(size_t)c * N + rowbase + rr] = val;
        }
    }
}

// ---------------- row FFT: 4 real rows per wave = 2 interleaved packed FFTs ----
__global__ __launch_bounds__(512, 4) void rowfft_kernel(const float* __restrict__ x,
                                                        const float* __restrict__ htab,
                                                        float* __restrict__ meanacc,
                                                        __half2* __restrict__ inter) {
    __shared__ float sm[9216];      // 36,864 B: 8 waves x 576 float2; tile [32][265] half2 overlaps
    __shared__ float redsum[8];
    int tid = threadIdx.x;
    int w = tid >> 6, l = tid & 63;
    int img = blockIdx.x >> 4;
    int rowbase = (blockIdx.x & 15) << 5;
    int r1 = rowbase + 4 * w;
    int rl = __brev((unsigned)l) >> 26;                 // brev6(l)
    const int bre[8] = {0, 4, 2, 6, 1, 5, 3, 7};        // brev3(e)
    const float* xp = x + ((size_t)img * N + r1) * N + rl;
    const float* hp = htab + (size_t)r1 * N + rl;

    float ax[4][8], hx[4][8];
#pragma unroll
    for (int j = 0; j < 4; j++)
#pragma unroll
        for (int e = 0; e < 8; e++) ax[j][e] = xp[j * N + (bre[e] << 6)];
#pragma unroll
    for (int j = 0; j < 4; j++)
#pragma unroll
        for (int e = 0; e < 8; e++) hx[j][e] = hp[j * N + (bre[e] << 6)];
    // pin: all 64 loads issued (and live) before any use -> one latency, not eight
    __builtin_amdgcn_sched_barrier(0);

    float rsum = 0.0f;
#pragma unroll
    for (int j = 0; j < 4; j++)
#pragma unroll
        for (int e = 0; e < 8; e++) rsum += ax[j][e];

    float2 va[8], vb[8];
#pragma unroll
    for (int e = 0; e < 8; e++) {
        va[e] = make_float2(ax[0][e] * hx[0][e], ax[1][e] * hx[1][e]);
        vb[e] = make_float2(ax[2][e] * hx[2][e], ax[3][e] * hx[3][e]);
    }

#pragma unroll
    for (int off = 32; off > 0; off >>= 1) rsum += __shfl_down(rsum, off);
    if (l == 0) redsum[w] = rsum;

    float2* st = (float2*)sm + w * 576;
    fft512_x2(va, vb, st, l);
    __syncthreads();   // all waves done with FFT scratch before tile reuse
    if (tid == 0) {
        float s = 0.0f;
#pragma unroll
        for (int i = 0; i < 8; i++) s += redsum[i];
        atomicAdd(meanacc + img, s);
    }

    __half2* tile = (__half2*)sm;    // [32][265]
    int sl = (64 - l) & 63;
    unpack_rows(va, tile, 4 * w, 4 * w + 1, l, sl);
    unpack_rows(vb, tile, 4 * w + 2, 4 * w + 3, l, sl);
    __syncthreads();

    // coalesced transposed write: 32 consecutive rows per column
    int c0 = tid >> 5, rr = tid & 31;
#pragma unroll
    for (int it = 0; it < 17; it++) {
        int c = it * 16 + c0;
        if (c < NF) {
            inter[((size_t)img * NF + c) * N + rowbase + rr] = tile[rr * 265 + c];
        }
    }
}

// ---------------- column FFT + |F|^2 half-plane accumulate ----------------
// 4 waves = 4 columns per block; 4 images per y-group = 2 interleaved FFT pairs.
__global__ __launch_bounds__(256, 4) void colfft_kernel(const __half2* __restrict__ inter,
                                                        const float2* __restrict__ Hrow,
                                                        const float* __restrict__ meanacc,
                                                        float* __restrict__ accH) {
    __shared__ float sm[4608];
    int tid = threadIdx.x;
    int w = tid >> 6, l = tid & 63;
    int col = blockIdx.x * 4 + w;
    int colc = col < NF ? col : NF - 1;
    int b0 = blockIdx.y * 4;
    float2* st = (float2*)sm + w * 576;
    int rl = __brev((unsigned)l) >> 26;                 // brev6(l)
    const int bre[8] = {0, 4, 2, 6, 1, 5, 3, 7};        // brev3(e)

    float2 hc[8];
    const float2* hp = Hrow + (size_t)colc * N + rl;
#pragma unroll
    for (int e = 0; e < 8; e++) hc[e] = hp[bre[e] << 6];

    float mn[4];
#pragma unroll
    for (int i = 0; i < 4; i++)
        mn[i] = meanacc[b0 + i] * (1.0f / ((float)N * (float)N));

    float pw[8];
#pragma unroll
    for (int t = 0; t < 8; t++) pw[t] = 0.0f;

    const size_t istr = (size_t)NF * N;
    const __half2* base = inter + ((size_t)b0 * NF + colc) * N + rl;

    __half2 cA[8], cB[8], nA[8], nB[8];
#pragma unroll
    for (int e = 0; e < 8; e++) {
        cA[e] = base[bre[e] << 6];
        cB[e] = base[istr + (bre[e] << 6)];
    }
    __builtin_amdgcn_sched_barrier(0);

#pragma unroll
    for (int it = 0; it < 2; it++) {
        if (it == 0) {
#pragma unroll
            for (int e = 0; e < 8; e++) {
                nA[e] = base[2 * istr + (bre[e] << 6)];
                nB[e] = base[3 * istr + (bre[e] << 6)];
            }
        }
        float mA = mn[2 * it], mB = mn[2 * it + 1];
        float2 va[8], vb[8];
#pragma unroll
        for (int e = 0; e < 8; e++) {
            float2 zA = __half22float2(cA[e]);
            float2 zB = __half22float2(cB[e]);
            va[e] = make_float2(zA.x - mA * hc[e].x, zA.y - mA * hc[e].y);
            vb[e] = make_float2(zB.x - mB * hc[e].x, zB.y - mB * hc[e].y);
        }
        fft512_x2(va, vb, st, l);
#pragma unroll
        for (int t = 0; t < 8; t++)
            pw[t] += va[t].x * va[t].x + va[t].y * va[t].y
                   + vb[t].x * vb[t].x + vb[t].y * vb[t].y;
#pragma unroll
        for (int e = 0; e < 8; e++) { cA[e] = nA[e]; cB[e] = nB[e]; }
    }

    if (col < NF) {
#pragma unroll
        for (int t = 0; t < 8; t++)
            atomicAdd(&accH[(size_t)col * N + 64 * t + l], pw[t]);
    }
}

// ---------------- finalize: nps2D (with Hermitian mirror) + radial bins ------
__global__ __launch_bounds__(256) void finalize2d_kernel(const float* __restrict__ accH,
                                                         float* __restrict__ out2d,
                                                         float* __restrict__ bins) {
    __shared__ float lsum[NF];
    __shared__ float lcnt[NF];
    int t = threadIdx.x;
    for (int i = t; i < NF; i += 256) { lsum[i] = 0.0f; lcnt[i] = 0.0f; }
    __syncthreads();
    const float scale = (0.1f * 0.1f) / ((float)N * (float)N) / (float)NB;
    int idx = blockIdx.x * 256 + t;
    int stride = gridDim.x * 256;
    for (int p = idx; p < N * N; p += stride) {
        int i = p >> 9, j = p & (N - 1);
        int jm = (j + 256) & 511;
        int col, k;
        if (jm < NF) { col = jm; k = (i + 256) & 511; }        // direct half-plane
        else         { col = 256 - j; k = (256 - i) & 511; }   // Hermitian mirror
        float v = accH[((size_t)col << 9) + k] * scale;
        out2d[p] = v;                                           // coalesced store
        float xi = (float)(i - 256), yj = (float)(j - 256);
        int rad = (int)rintf(sqrtf(xi * xi + yj * yj));
        if (rad < NF) { atomicAdd(&lsum[rad], v); atomicAdd(&lcnt[rad], 1.0f); }
    }
    __syncthreads();
    for (int i = t; i < NF; i += 256) {
        if (lsum[i] != 0.0f || lcnt[i] != 0.0f) {
            atomicAdd(&bins[i], lsum[i]);
            atomicAdd(&bins[NF + 1 + i], lcnt[i]);
        }
    }
}

// ---------------- finalize: nps1D + f1D ----------------
__global__ void finalize1d_kernel(const float* __restrict__ bins, float* __restrict__ out) {
    int t = blockIdx.x * blockDim.x + threadIdx.x;
    if (t < NF) {
        out[t] = bins[t] / bins[NF + 1 + t];                 // nps1D
        out[NF + N * N + t] = (float)t * (5.0f / 256.0f);    // f1D (nyquist = 5)
    }
}

extern "C" void kernel_launch(void* const* d_in, const int* in_sizes, int n_in,
                              void* d_out, int out_size, void* d_ws, size_t ws_size,
                              hipStream_t stream) {
    const float* x = (const float*)d_in[0];
    float* out = (float*)d_out;
    char* ws = (char*)d_ws;

    float* accH    = (float*)ws;                                     // NF*N floats
    float* meanacc = (float*)(ws + (size_t)NF * N * sizeof(float));  // NB floats
    float* bins    = meanacc + NB;                                   // 2*(NF+1) floats
    size_t off_h = (size_t)NF * N * sizeof(float) + NB * sizeof(float)
                   + 2 * (NF + 1) * sizeof(float);
    off_h = (off_h + 255) & ~(size_t)255;
    float2* Hrow = (float2*)(ws + off_h);                            // [NF][N] float2 ~ 1.05 MB
    size_t off_t = off_h + (size_t)NF * N * sizeof(float2);
    off_t = (off_t + 255) & ~(size_t)255;
    float* htab = (float*)(ws + off_t);                              // [N][N] float = 1 MB
    size_t off_inter = off_t + (size_t)N * N * sizeof(float);
    off_inter = (off_inter + 255) & ~(size_t)255;
    __half2* inter = (__half2*)(ws + off_inter);   // [NB][NF][N] half2 = 67.4 MB

    zero_kernel<<<dim3((NF * N + 255) / 256), dim3(256), 0, stream>>>(accH, bins, meanacc);
    hanntab_kernel<<<dim3(N * N / 256), dim3(256), 0, stream>>>(htab);
    hannfft_kernel<<<dim3(32), dim3(512), 0, stream>>>(htab, Hrow);
    rowfft_kernel<<<dim3(NB * 16), dim3(512), 0, stream>>>(x, htab, meanacc, inter);
    colfft_kernel<<<dim3(65, 32), dim3(256), 0, stream>>>(inter, Hrow, meanacc, accH);
    finalize2d_kernel<<<dim3(256), dim3(256), 0, stream>>>(accH, out + NF, bins);
    finalize1d_kernel<<<dim3(2), dim3(256), 0, stream>>>(bins, out);
}